// Round 1
// baseline (714.676 us; speedup 1.0000x reference)
//
#include <hip/hip_runtime.h>
#include <cstdint>
#include <cstddef>

// ---------------------------------------------------------------------------
// DHSEncoderLayer on MI355X (gfx950).
// B=4,S=2048,D=128,H=4,HD=32,V=64, ITERS=3. Outputs: x [B,S,D] f32, aw [B,H,S,S] f32.
// All heavy GEMMs via mfma_f32_16x16x32_bf16 (fp32 accum). infl term skipped
// (softmax shift-invariance). Attention computed as S^T = K·Q^T tiles so
// softmax stats live per-lane; no max-subtraction (|scores| << 1).
// Workspace use: ~41 MB.
// ---------------------------------------------------------------------------

typedef unsigned short u16;
typedef __attribute__((ext_vector_type(8))) short short8;   // 8 x bf16
typedef __attribute__((ext_vector_type(4))) short short4v;  // 4 x bf16 (8B)
typedef __attribute__((ext_vector_type(4))) float f32x4;

#define B_ 4
#define S_ 2048
#define D_ 128
#define H_ 4
#define M_ 8192            // B*S
#define SCALE_ 0.17677669529663687f
#define APO_ 0.2f
#define TRP_ 0.15f
#define EPS_ 1e-5f

__device__ __forceinline__ u16 f2bf(float f){
  unsigned u = __float_as_uint(f);
  unsigned r = ((u >> 16) & 1u) + 0x7fffu;     // round-to-nearest-even
  return (u16)((u + r) >> 16);
}
__device__ __forceinline__ float bf2f(u16 u){ return __uint_as_float(((unsigned)u) << 16); }
__device__ __forceinline__ float sigm(float x){ return 1.0f/(1.0f + __expf(-x)); }

// ---------------------------------------------------------------- weight cvt
struct WSrc { const float* s[13]; };
// order: Wq,Wk,Wv | Wo | Wg | Wt | Ws | Wr | Wop | W1 | W2 | Wsg | Wn
__global__ __launch_bounds__(256) void cvt_weights(WSrc w, u16* __restrict__ dst){
  int idx = blockIdx.x*256 + threadIdx.x;
  if (idx >= 299008) return;
  const int sz[13] = {16384,16384,16384,16384,32768,8192,8192,12288,8192,65536,65536,16384,16384};
  int off = idx;
  #pragma unroll
  for (int seg = 0; seg < 13; ++seg){
    if (off < sz[seg]) { dst[idx] = f2bf(w.s[seg][off]); return; }
    off -= sz[seg];
  }
}

__global__ __launch_bounds__(256) void f2bf_k(const float* __restrict__ src, u16* __restrict__ dst, int n){
  int i = blockIdx.x*256 + threadIdx.x;
  if (i < n) dst[i] = f2bf(src[i]);
}

// ---------------------------------------------------------------- layernorm
// one wave per row (128 elems, 2/lane). Optional residual add (in1),
// optional store of pre-LN sum, bf16 output with row stride ldy, optional f32 out.
__global__ __launch_bounds__(256) void ln_kernel(const float* __restrict__ in0,
    const float* __restrict__ in1, const float* __restrict__ g, const float* __restrict__ b,
    float* __restrict__ sumout, u16* __restrict__ ybf, int ldy, float* __restrict__ yf32){
  int wv = threadIdx.x >> 6, lane = threadIdx.x & 63;
  int row = blockIdx.x*4 + wv;
  size_t rb = (size_t)row * D_;
  float v0 = in0[rb + lane], v1 = in0[rb + lane + 64];
  if (in1){ v0 += in1[rb + lane]; v1 += in1[rb + lane + 64]; }
  if (sumout){ sumout[rb + lane] = v0; sumout[rb + lane + 64] = v1; }
  float s = v0 + v1;
  #pragma unroll
  for (int m = 1; m < 64; m <<= 1) s += __shfl_xor(s, m, 64);
  float mean = s * (1.0f/128.0f);
  float d0 = v0 - mean, d1 = v1 - mean;
  float vv = d0*d0 + d1*d1;
  #pragma unroll
  for (int m = 1; m < 64; m <<= 1) vv += __shfl_xor(vv, m, 64);
  float rstd = rsqrtf(vv * (1.0f/128.0f) + EPS_);
  float y0 = d0*rstd*g[lane]      + b[lane];
  float y1 = d1*rstd*g[lane+64]   + b[lane+64];
  ybf[(size_t)row*ldy + lane]      = f2bf(y0);
  ybf[(size_t)row*ldy + lane + 64] = f2bf(y1);
  if (yf32){ yf32[rb + lane] = y0; yf32[rb + lane + 64] = y1; }
}

// ---------------------------------------------------------------- small TRP kernels
__global__ __launch_bounds__(256) void colmean_k(const u16* __restrict__ lnb, float* __restrict__ cm){
  __shared__ float red[2][128];
  int b = blockIdx.x;
  int d = threadIdx.x & 127, sc = threadIdx.x >> 7;
  const u16* pp = lnb + (size_t)b*S_*D_ + (size_t)sc*1024*D_ + d;
  float s = 0.f;
  #pragma unroll 8
  for (int i = 0; i < 1024; ++i) s += bf2f(pp[(size_t)i*D_]);
  red[sc][d] = s;
  __syncthreads();
  if (sc == 0) cm[b*D_ + d] = (red[0][d] + red[1][d]) * (1.0f/2048.0f);
}

__global__ __launch_bounds__(256) void cv_k(const float* __restrict__ cm, const float* __restrict__ Wc,
    const float* __restrict__ bc, float* __restrict__ cv, float* __restrict__ cn){
  int tid = threadIdx.x; int b = tid >> 6, n = tid & 63;
  const float* mrow = cm + b*D_;
  const float* wrow = Wc + n*D_;
  float s = bc[n];
  #pragma unroll 4
  for (int d = 0; d < D_; ++d) s += mrow[d]*wrow[d];
  cv[b*64 + n] = s;
  float sq = s*s;
  #pragma unroll
  for (int m = 1; m < 64; m <<= 1) sq += __shfl_xor(sq, m, 64);
  if (n == 0) cn[b] = fmaxf(sqrtf(sq), 1e-8f);
}

__global__ __launch_bounds__(256) void bcast_k(const float* __restrict__ cv, u16* __restrict__ cg2){
  int idx = blockIdx.x*256 + threadIdx.x;           // M_*64 total
  int row = idx >> 6, n = idx & 63;
  cg2[(size_t)row*192 + 64 + n] = f2bf(cv[(row >> 11)*64 + n]);
}

__global__ __launch_bounds__(256) void align_k(const float* __restrict__ sv, const float* __restrict__ cv,
    const float* __restrict__ cn, float* __restrict__ alignb){
  int wv = threadIdx.x >> 6, lane = threadIdx.x & 63;
  int row = blockIdx.x*4 + wv; int b = row >> 11;
  float s = sv[(size_t)row*64 + lane];
  float c = cv[b*64 + lane];
  float dot = c*s, ss = s*s;
  #pragma unroll
  for (int m = 1; m < 64; m <<= 1){ dot += __shfl_xor(dot, m, 64); ss += __shfl_xor(ss, m, 64); }
  if (lane == 0){
    float sn = fmaxf(sqrtf(ss), 1e-8f);
    alignb[row] = dot / (cn[b]*sn);
  }
}

// ---------------------------------------------------------------- generic MFMA GEMM
struct Ptrs {
  const float *bo,*bg,*bt,*bs,*br,*fv,*bop,*b1,*b2,*bsg,*bn;
  u16 *qh,*kh,*vt,*cg2,*res_bf,*mid;
  float *cur,*outb,*xbuf,*tv,*sv,*alignb,*ff,*out_x;
};

enum { E_QKV, E_WO, E_WG, E_TV, E_SV, E_RG, E_WOP, E_W1, E_W2, E_WSG, E_WN };

template<int EPI>
__device__ __forceinline__ void epi_store(int m, int n, float val, const Ptrs& p, u16* __restrict__ ebf){
  if constexpr (EPI == E_QKV){
    int which = n >> 7, col = n & 127, h = col >> 5, hd = col & 31;
    int b = m >> 11, s = m & 2047;
    if (which == 0)      p.qh[((size_t)(b*H_+h)*S_ + s)*32 + hd] = f2bf(val);
    else if (which == 1) p.kh[((size_t)(b*H_+h)*S_ + s)*32 + hd] = f2bf(val);
    else                 p.vt[((size_t)(b*H_+h)*32 + hd)*S_ + s] = f2bf(val);
  } else if constexpr (EPI == E_WO){
    float v = val + p.bo[n];
    p.outb[(size_t)m*D_ + n] = v;
    ebf[(size_t)m*256 + n] = f2bf(v);                   // ebf = cg_in + 128
  } else if constexpr (EPI == E_WG){
    float g = sigm(val + p.bg[n]);
    size_t i = (size_t)m*D_ + n;
    float c = p.cur[i], o = p.outb[i];
    float nc = c + g*(o - c);
    p.cur[i] = nc;
    ebf[(size_t)m*256 + n] = f2bf(nc);                  // ebf = cg_out
  } else if constexpr (EPI == E_TV){
    float v = val + p.bt[n];
    p.tv[(size_t)m*64 + n] = v;
    p.cg2[(size_t)m*192 + n] = f2bf(v);
  } else if constexpr (EPI == E_SV){
    float v = val + p.bs[n];
    p.sv[(size_t)m*64 + n] = v;
    p.cg2[(size_t)m*192 + 128 + n] = f2bf(v);
  } else if constexpr (EPI == E_RG){
    float rg = sigm(val + p.br[n]);
    float t = p.tv[(size_t)m*64 + n];
    float al = p.alignb[m];
    float res = t + TRP_*(-al*(p.fv[n] - t)*rg);
    p.res_bf[(size_t)m*64 + n] = f2bf(res);
  } else if constexpr (EPI == E_WOP){
    p.xbuf[(size_t)m*D_ + n] += val + p.bop[n];
  } else if constexpr (EPI == E_W1){
    float lin = val + p.b1[n];
    float ge = 0.5f*lin*(1.0f + erff(lin*0.70710678118654752f));
    p.mid[(size_t)m*512 + n] = f2bf(ge);
  } else if constexpr (EPI == E_W2){
    p.ff[(size_t)m*D_ + n] = val + p.b2[n];
  } else if constexpr (EPI == E_WSG){
    float sg = sigm(val + p.bsg[n]);
    p.xbuf[(size_t)m*D_ + n] += sg * p.ff[(size_t)m*D_ + n];
  } else if constexpr (EPI == E_WN){
    float lin = val + p.bn[n];
    p.out_x[(size_t)m*D_ + n] = p.xbuf[(size_t)m*D_ + n] - APO_*tanhf(lin);
  }
}

// C[m,n] = sum_k A[m,k]*W[n,k];  A bf16 [M,lda-strided], W bf16 [N,K] row-major.
// block tile 64x64, 4 waves (2x2 of 32x32), K-chunks of 32 (one mfma each).
template<int EPI>
__global__ __launch_bounds__(256) void gemm_k(const u16* __restrict__ A, int lda,
    const u16* __restrict__ W, int K, Ptrs p, u16* __restrict__ ebf){
  __shared__ u16 Asm[64*40];
  __shared__ u16 Bsm[64*40];
  const int m0 = blockIdx.x*64, n0 = blockIdx.y*64;
  int tid = threadIdx.x;
  int wv = tid >> 6, lane = tid & 63, quad = lane >> 4, l15 = lane & 15;
  int wm = wv >> 1, wn = wv & 1;
  int sr = tid >> 2, sc = (tid & 3)*8;
  f32x4 acc[2][2];
  #pragma unroll
  for (int i = 0; i < 2; ++i)
    #pragma unroll
    for (int j = 0; j < 2; ++j) acc[i][j] = (f32x4){0.f,0.f,0.f,0.f};

  for (int k0 = 0; k0 < K; k0 += 32){
    short8 av = *(const short8*)(A + (size_t)(m0 + sr)*lda + k0 + sc);
    short8 wvv = *(const short8*)(W + (size_t)(n0 + sr)*K  + k0 + sc);
    __syncthreads();
    *(short8*)(Asm + sr*40 + sc) = av;
    *(short8*)(Bsm + sr*40 + sc) = wvv;
    __syncthreads();
    short8 af0 = *(const short8*)(Asm + (wm*32      + l15)*40 + quad*8);
    short8 af1 = *(const short8*)(Asm + (wm*32 + 16 + l15)*40 + quad*8);
    short8 bf0 = *(const short8*)(Bsm + (wn*32      + l15)*40 + quad*8);
    short8 bf1 = *(const short8*)(Bsm + (wn*32 + 16 + l15)*40 + quad*8);
    acc[0][0] = __builtin_amdgcn_mfma_f32_16x16x32_bf16(af0, bf0, acc[0][0], 0,0,0);
    acc[0][1] = __builtin_amdgcn_mfma_f32_16x16x32_bf16(af0, bf1, acc[0][1], 0,0,0);
    acc[1][0] = __builtin_amdgcn_mfma_f32_16x16x32_bf16(af1, bf0, acc[1][0], 0,0,0);
    acc[1][1] = __builtin_amdgcn_mfma_f32_16x16x32_bf16(af1, bf1, acc[1][1], 0,0,0);
  }
  #pragma unroll
  for (int ms = 0; ms < 2; ++ms)
    #pragma unroll
    for (int ns = 0; ns < 2; ++ns){
      int mb = m0 + wm*32 + ms*16 + quad*4;
      int nn = n0 + wn*32 + ns*16 + l15;
      f32x4 c = acc[ms][ns];
      #pragma unroll
      for (int r = 0; r < 4; ++r) epi_store<EPI>(mb + r, nn, c[r], p, ebf);
    }
}

// ---------------------------------------------------------------- fused attention
// grid (S/64, B*H), 256 thr. Wave w owns q rows [q0+16w, q0+16w+16).
// S^T = K·Q^T tiles: C-layout col=q (lane&15), row=j (quad*4+r).
// WRITE_AW: pass1 computes l (sum exp), pass2 writes exact aw + PV.
template<bool WRITE_AW>
__global__ __launch_bounds__(256) void attn_k(const u16* __restrict__ qh, const u16* __restrict__ kh,
    const u16* __restrict__ vT, u16* __restrict__ ao_bf, float* __restrict__ aw){
  __shared__ u16 Ks[64*40];
  __shared__ u16 Vs[32*72];
  __shared__ u16 Ps[4*16*72];
  int bh = blockIdx.y; int b = bh >> 2, h = bh & 3;
  int q0 = blockIdx.x*64;
  int tid = threadIdx.x, wv = tid >> 6, lane = tid & 63, quad = lane >> 4, l15 = lane & 15;
  int qrow = q0 + wv*16 + l15;
  const size_t bhS = (size_t)bh * S_;
  short8 qf = *(const short8*)(qh + (bhS + qrow)*32 + quad*8);
  int kr = tid >> 2, kc = (tid & 3)*8;    // K tile [64][32]
  int vr = tid >> 3, vc = (tid & 7)*8;    // V^T tile [32][64]
  f32x4 zero = {0.f,0.f,0.f,0.f};
  f32x4 ao0 = zero, ao1 = zero;
  float lsum = 0.f, rinv = 1.0f;

  if constexpr (WRITE_AW){
    for (int k0 = 0; k0 < S_; k0 += 64){
      __syncthreads();
      *(short8*)(Ks + kr*40 + kc) = *(const short8*)(kh + (bhS + k0 + kr)*32 + kc);
      __syncthreads();
      #pragma unroll
      for (int jt = 0; jt < 4; ++jt){
        short8 kf = *(const short8*)(Ks + (jt*16 + l15)*40 + quad*8);
        f32x4 s = __builtin_amdgcn_mfma_f32_16x16x32_bf16(kf, qf, zero, 0,0,0);
        #pragma unroll
        for (int r = 0; r < 4; ++r) lsum += __expf(s[r]*SCALE_);
      }
    }
    lsum += __shfl_xor(lsum, 16, 64);
    lsum += __shfl_xor(lsum, 32, 64);
    rinv = 1.0f / lsum;
  }

  for (int k0 = 0; k0 < S_; k0 += 64){
    __syncthreads();
    *(short8*)(Ks + kr*40 + kc) = *(const short8*)(kh + (bhS + k0 + kr)*32 + kc);
    *(short8*)(Vs + vr*72 + vc) = *(const short8*)(vT + ((size_t)bh*32 + vr)*S_ + k0 + vc);
    __syncthreads();
    #pragma unroll
    for (int jt = 0; jt < 4; ++jt){
      short8 kf = *(const short8*)(Ks + (jt*16 + l15)*40 + quad*8);
      f32x4 s = __builtin_amdgcn_mfma_f32_16x16x32_bf16(kf, qf, zero, 0,0,0);
      float pv[4];
      #pragma unroll
      for (int r = 0; r < 4; ++r){
        float e = __expf(s[r]*SCALE_);
        if constexpr (WRITE_AW) e *= rinv; else lsum += e;
        pv[r] = e;
      }
      if constexpr (WRITE_AW){
        f32x4 st = {pv[0], pv[1], pv[2], pv[3]};
        *(f32x4*)(aw + (bhS + qrow)*S_ + k0 + jt*16 + quad*4) = st;
      }
      short4v pk;
      pk[0] = (short)f2bf(pv[0]); pk[1] = (short)f2bf(pv[1]);
      pk[2] = (short)f2bf(pv[2]); pk[3] = (short)f2bf(pv[3]);
      *(short4v*)(Ps + (wv*16 + l15)*72 + jt*16 + quad*4) = pk;
    }
    __asm__ volatile("s_waitcnt lgkmcnt(0)" ::: "memory");
    #pragma unroll
    for (int jg = 0; jg < 2; ++jg){
      short8 pf  = *(const short8*)(Ps + (wv*16 + l15)*72 + jg*32 + quad*8);
      short8 vf0 = *(const short8*)(Vs + (l15     )*72 + jg*32 + quad*8);
      short8 vf1 = *(const short8*)(Vs + (16 + l15)*72 + jg*32 + quad*8);
      ao0 = __builtin_amdgcn_mfma_f32_16x16x32_bf16(vf0, pf, ao0, 0,0,0);
      ao1 = __builtin_amdgcn_mfma_f32_16x16x32_bf16(vf1, pf, ao1, 0,0,0);
    }
  }

  if constexpr (!WRITE_AW){
    lsum += __shfl_xor(lsum, 16, 64);
    lsum += __shfl_xor(lsum, 32, 64);
    rinv = 1.0f / lsum;
  } else rinv = 1.0f;

  size_t rowbase = ((size_t)(b*S_ + qrow))*D_ + h*32;
  #pragma unroll
  for (int dt = 0; dt < 2; ++dt){
    f32x4 a = dt ? ao1 : ao0;
    short4v pk;
    #pragma unroll
    for (int r = 0; r < 4; ++r) pk[r] = (short)f2bf(a[r]*rinv);
    *(short4v*)(ao_bf + rowbase + dt*16 + quad*4) = pk;
  }
}

// ---------------------------------------------------------------- launch
extern "C" void kernel_launch(void* const* d_in, const int* in_sizes, int n_in,
                              void* d_out, int out_size, void* d_ws, size_t ws_size,
                              hipStream_t stream){
  (void)in_sizes; (void)n_in; (void)out_size; (void)ws_size;
  const float* x_in   = (const float*)d_in[0];
  const float* space  = (const float*)d_in[1];
  const float* g_attn = (const float*)d_in[2];
  const float* b_attn = (const float*)d_in[3];
  const float* Wq     = (const float*)d_in[4];
  const float* Wk     = (const float*)d_in[5];
  const float* Wv     = (const float*)d_in[6];
  const float* Wo     = (const float*)d_in[7];
  const float* bo     = (const float*)d_in[8];
  const float* Wg     = (const float*)d_in[9];
  const float* bg     = (const float*)d_in[10];
  // d_in[11] Wobs, d_in[12] bobs: dead (softmax shift-invariance)
  const float* g_trp  = (const float*)d_in[13];
  const float* b_trp  = (const float*)d_in[14];
  const float* Wt     = (const float*)d_in[15];
  const float* bt     = (const float*)d_in[16];
  const float* Wc     = (const float*)d_in[17];
  const float* bc     = (const float*)d_in[18];
  const float* Ws_    = (const float*)d_in[19];
  const float* bs     = (const float*)d_in[20];
  const float* Wr     = (const float*)d_in[21];
  const float* br     = (const float*)d_in[22];
  const float* fv     = (const float*)d_in[23];
  const float* Wop    = (const float*)d_in[24];
  const float* bop    = (const float*)d_in[25];
  const float* g_ffn  = (const float*)d_in[26];
  const float* b_ffn  = (const float*)d_in[27];
  const float* W1_    = (const float*)d_in[28];
  const float* b1     = (const float*)d_in[29];
  const float* W2_    = (const float*)d_in[30];
  const float* b2     = (const float*)d_in[31];
  const float* Wsg_   = (const float*)d_in[32];
  const float* bsg    = (const float*)d_in[33];
  const float* g_apo  = (const float*)d_in[34];
  const float* b_apo  = (const float*)d_in[35];
  const float* Wn_    = (const float*)d_in[36];
  const float* bn     = (const float*)d_in[37];

  char* base = (char*)d_ws;
  size_t off = 0;
  auto alloc = [&](size_t bytes)->char* {
    char* r = base + off; off += (bytes + 255) & ~(size_t)255; return r; };
  u16*  wbf      = (u16*) alloc((size_t)299008*2);
  u16*  space_bf = (u16*) alloc((size_t)M_*D_*2);
  u16*  cg0      = (u16*) alloc((size_t)M_*256*2);
  u16*  cg1      = (u16*) alloc((size_t)M_*256*2);
  float* cur     = (float*)alloc((size_t)M_*D_*4);
  float* outb    = (float*)alloc((size_t)M_*D_*4);
  float* xbuf    = (float*)alloc((size_t)M_*D_*4);
  u16*  qh       = (u16*) alloc((size_t)16*S_*32*2);
  u16*  kh       = (u16*) alloc((size_t)16*S_*32*2);
  u16*  vt       = (u16*) alloc((size_t)16*32*S_*2);
  u16*  ao_bf    = (u16*) alloc((size_t)M_*D_*2);
  u16*  lnb      = (u16*) alloc((size_t)M_*D_*2);
  float* tv      = (float*)alloc((size_t)M_*64*4);
  float* svb     = (float*)alloc((size_t)M_*64*4);
  u16*  cg2      = (u16*) alloc((size_t)M_*192*2);
  u16*  res_bf   = (u16*) alloc((size_t)M_*64*2);
  float* colmean = (float*)alloc(4*128*4);
  float* cv      = (float*)alloc(4*64*4);
  float* cn      = (float*)alloc(4*4);
  float* alignb  = (float*)alloc((size_t)M_*4);
  u16*  mid      = qh;    // FFN mid [M,512] bf16 aliases qh..ao_bf (attention done)
  float* ff      = outb;  // outb dead after attention loop

  u16* wqkv = wbf;           // [384,128]: Wq|Wk|Wv stacked
  u16* wo   = wbf + 49152;   // [128,128]
  u16* wg   = wbf + 65536;   // [128,256]
  u16* wt   = wbf + 98304;   // [64,128]
  u16* wsx  = wbf + 106496;  // [64,128]
  u16* wr   = wbf + 114688;  // [64,192]
  u16* wop  = wbf + 126976;  // [128,64]
  u16* w1   = wbf + 135168;  // [512,128]
  u16* w2   = wbf + 200704;  // [128,512]
  u16* wsgp = wbf + 266240;  // [128,128]
  u16* wn   = wbf + 282624;  // [128,128]

  float* out_x = (float*)d_out;
  float* aw    = out_x + (size_t)M_*D_;

  Ptrs p;
  p.bo=bo; p.bg=bg; p.bt=bt; p.bs=bs; p.br=br; p.fv=fv; p.bop=bop;
  p.b1=b1; p.b2=b2; p.bsg=bsg; p.bn=bn;
  p.qh=qh; p.kh=kh; p.vt=vt; p.cg2=cg2; p.res_bf=res_bf; p.mid=mid;
  p.cur=cur; p.outb=outb; p.xbuf=xbuf; p.tv=tv; p.sv=svb; p.alignb=alignb;
  p.ff=ff; p.out_x=out_x;

  WSrc wsrc;
  wsrc.s[0]=Wq; wsrc.s[1]=Wk; wsrc.s[2]=Wv; wsrc.s[3]=Wo; wsrc.s[4]=Wg;
  wsrc.s[5]=Wt; wsrc.s[6]=Ws_; wsrc.s[7]=Wr; wsrc.s[8]=Wop; wsrc.s[9]=W1_;
  wsrc.s[10]=W2_; wsrc.s[11]=Wsg_; wsrc.s[12]=Wn_;

  cvt_weights<<<1168, 256, 0, stream>>>(wsrc, wbf);
  f2bf_k<<<(M_*D_+255)/256, 256, 0, stream>>>(space, space_bf, M_*D_);

  // xn = LN(x); cur = xn (f32) ; cg0[:, :128] = bf16(xn)
  ln_kernel<<<M_/4, 256, 0, stream>>>(x_in, nullptr, g_attn, b_attn, nullptr, cg0, 256, cur);

  u16* cgs[2] = {cg0, cg1};
  for (int it = 0; it < 3; ++it){
    u16* cin  = cgs[it & 1];
    u16* cout = cgs[(it + 1) & 1];
    gemm_k<E_QKV><<<dim3(M_/64, 6), 256, 0, stream>>>(cin, 256, wqkv, 128, p, nullptr);
    if (it == 2) attn_k<true ><<<dim3(S_/64, 16), 256, 0, stream>>>(qh, kh, vt, ao_bf, aw);
    else         attn_k<false><<<dim3(S_/64, 16), 256, 0, stream>>>(qh, kh, vt, ao_bf, nullptr);
    gemm_k<E_WO ><<<dim3(M_/64, 2), 256, 0, stream>>>(ao_bf, 128, wo, 128, p, cin + 128);
    gemm_k<E_WG ><<<dim3(M_/64, 2), 256, 0, stream>>>(cin, 256, wg, 256, p, cout);
  }

  // x = x_in + cur (stored to xbuf); xn2 = LN -> lnb bf16
  ln_kernel<<<M_/4, 256, 0, stream>>>(x_in, cur, g_trp, b_trp, xbuf, lnb, 128, nullptr);
  colmean_k<<<4, 256, 0, stream>>>(lnb, colmean);
  cv_k<<<1, 256, 0, stream>>>(colmean, Wc, bc, cv, cn);
  bcast_k<<<(M_*64)/256, 256, 0, stream>>>(cv, cg2);
  gemm_k<E_TV ><<<dim3(M_/64, 1), 256, 0, stream>>>(lnb, 128, wt, 128, p, nullptr);
  gemm_k<E_SV ><<<dim3(M_/64, 1), 256, 0, stream>>>(space_bf, 128, wsx, 128, p, nullptr);
  align_k<<<M_/4, 256, 0, stream>>>(svb, cv, cn, alignb);
  gemm_k<E_RG ><<<dim3(M_/64, 1), 256, 0, stream>>>(cg2, 192, wr, 192, p, nullptr);
  gemm_k<E_WOP><<<dim3(M_/64, 2), 256, 0, stream>>>(res_bf, 64, wop, 64, p, nullptr);

  // FFN
  ln_kernel<<<M_/4, 256, 0, stream>>>(xbuf, nullptr, g_ffn, b_ffn, nullptr, lnb, 128, nullptr);
  gemm_k<E_W1 ><<<dim3(M_/64, 8), 256, 0, stream>>>(lnb, 128, w1, 128, p, nullptr);
  gemm_k<E_W2 ><<<dim3(M_/64, 2), 256, 0, stream>>>(mid, 512, w2, 512, p, nullptr);
  gemm_k<E_WSG><<<dim3(M_/64, 2), 256, 0, stream>>>(lnb, 128, wsgp, 128, p, nullptr);

  // Apophasis
  ln_kernel<<<M_/4, 256, 0, stream>>>(xbuf, nullptr, g_apo, b_apo, nullptr, lnb, 128, nullptr);
  gemm_k<E_WN ><<<dim3(M_/64, 2), 256, 0, stream>>>(lnb, 128, wn, 128, p, nullptr);
}

// Round 3
// 597.188 us; speedup vs baseline: 1.1967x; 1.1967x over previous
//
#include <hip/hip_runtime.h>
#include <cstdint>
#include <cstddef>

// ---------------------------------------------------------------------------
// DHSEncoderLayer on MI355X (gfx950).  Round 3 = Round 2 fusion + exp2 fix.
// B=4,S=2048,D=128,H=4,HD=32,V=64, ITERS=3. Outputs: x [B,S,D] f32, aw [B,H,S,S] f32.
// 15 dispatches: cvt, ln1, [qkv, attn, wowg]x3, ln2, colmean, cv, uber.
// ---------------------------------------------------------------------------

typedef unsigned short u16;
typedef __attribute__((ext_vector_type(8))) short short8;   // 8 x bf16
typedef __attribute__((ext_vector_type(4))) short short4v;  // 4 x bf16 (8B)
typedef __attribute__((ext_vector_type(4))) float f32x4;

#define B_ 4
#define S_ 2048
#define D_ 128
#define H_ 4
#define M_ 8192            // B*S
#define SCALE2_ 0.25503472510324417f   // (1/sqrt(32)) * log2(e)
#define APO_ 0.2f
#define TRP_ 0.15f
#define EPS_ 1e-5f

__device__ __forceinline__ float fexp2(float x){ return __builtin_amdgcn_exp2f(x); }

__device__ __forceinline__ u16 f2bf(float f){
  unsigned u = __float_as_uint(f);
  unsigned r = ((u >> 16) & 1u) + 0x7fffu;     // round-to-nearest-even
  return (u16)((u + r) >> 16);
}
__device__ __forceinline__ float bf2f(u16 u){ return __uint_as_float(((unsigned)u) << 16); }
__device__ __forceinline__ float sigm(float x){ return 1.0f/(1.0f + __expf(-x)); }

// ---------------------------------------------------------------- weight cvt
struct WSrc { const float* s[13]; };
// order: Wq,Wk,Wv | Wo | Wg | Wt | Ws | Wr | Wop | W1 | W2 | Wsg | Wn
__global__ __launch_bounds__(256) void cvt_weights(WSrc w, u16* __restrict__ dst){
  int idx = blockIdx.x*256 + threadIdx.x;
  if (idx >= 299008) return;
  const int sz[13] = {16384,16384,16384,16384,32768,8192,8192,12288,8192,65536,65536,16384,16384};
  int off = idx;
  #pragma unroll
  for (int seg = 0; seg < 13; ++seg){
    if (off < sz[seg]) { dst[idx] = f2bf(w.s[seg][off]); return; }
    off -= sz[seg];
  }
}

// ---------------------------------------------------------------- layernorm
__global__ __launch_bounds__(256) void ln_kernel(const float* __restrict__ in0,
    const u16* __restrict__ in1bf, const float* __restrict__ g, const float* __restrict__ b,
    float* __restrict__ sumout, u16* __restrict__ ybf){
  int wv = threadIdx.x >> 6, lane = threadIdx.x & 63;
  int row = blockIdx.x*4 + wv;
  size_t rb = (size_t)row * D_;
  float v0 = in0[rb + lane], v1 = in0[rb + lane + 64];
  if (in1bf){ v0 += bf2f(in1bf[rb + lane]); v1 += bf2f(in1bf[rb + lane + 64]); }
  if (sumout){ sumout[rb + lane] = v0; sumout[rb + lane + 64] = v1; }
  float s = v0 + v1;
  #pragma unroll
  for (int m = 1; m < 64; m <<= 1) s += __shfl_xor(s, m, 64);
  float mean = s * (1.0f/128.0f);
  float d0 = v0 - mean, d1 = v1 - mean;
  float vv = d0*d0 + d1*d1;
  #pragma unroll
  for (int m = 1; m < 64; m <<= 1) vv += __shfl_xor(vv, m, 64);
  float rstd = rsqrtf(vv * (1.0f/128.0f) + EPS_);
  ybf[rb + lane]      = f2bf(d0*rstd*g[lane]    + b[lane]);
  ybf[rb + lane + 64] = f2bf(d1*rstd*g[lane+64] + b[lane+64]);
}

// ---------------------------------------------------------------- TRP cv path
__global__ __launch_bounds__(256) void colmean_k(const u16* __restrict__ lnb, float* __restrict__ cm){
  __shared__ float red[2][128];
  int b = blockIdx.x;
  int d = threadIdx.x & 127, sc = threadIdx.x >> 7;
  const u16* pp = lnb + (size_t)b*S_*D_ + (size_t)sc*1024*D_ + d;
  float s = 0.f;
  #pragma unroll 8
  for (int i = 0; i < 1024; ++i) s += bf2f(pp[(size_t)i*D_]);
  red[sc][d] = s;
  __syncthreads();
  if (sc == 0) cm[b*D_ + d] = (red[0][d] + red[1][d]) * (1.0f/2048.0f);
}

__global__ __launch_bounds__(256) void cv_k(const float* __restrict__ cm, const float* __restrict__ Wc,
    const float* __restrict__ bc, float* __restrict__ cv, float* __restrict__ cn){
  int tid = threadIdx.x; int b = tid >> 6, n = tid & 63;
  const float* mrow = cm + b*D_;
  const float* wrow = Wc + n*D_;
  float s = bc[n];
  #pragma unroll 4
  for (int d = 0; d < D_; ++d) s += mrow[d]*wrow[d];
  cv[b*64 + n] = s;
  float sq = s*s;
  #pragma unroll
  for (int m = 1; m < 64; m <<= 1) sq += __shfl_xor(sq, m, 64);
  if (n == 0) cn[b] = fmaxf(sqrtf(sq), 1e-8f);
}

// ---------------------------------------------------------------- QKV GEMM
__global__ __launch_bounds__(256) void gemm_qkv(const u16* __restrict__ A,
    const u16* __restrict__ W, u16* __restrict__ qh, u16* __restrict__ kh, u16* __restrict__ vt){
  __shared__ u16 Asm[64*40];
  __shared__ u16 Bsm[64*40];
  const int m0 = blockIdx.x*64, n0 = blockIdx.y*64;
  int tid = threadIdx.x;
  int wv = tid >> 6, lane = tid & 63, quad = lane >> 4, l15 = lane & 15;
  int wm = wv >> 1, wn = wv & 1;
  int sr = tid >> 2, sc = (tid & 3)*8;
  f32x4 acc[2][2];
  #pragma unroll
  for (int i = 0; i < 2; ++i)
    #pragma unroll
    for (int j = 0; j < 2; ++j) acc[i][j] = (f32x4){0.f,0.f,0.f,0.f};

  for (int k0 = 0; k0 < 128; k0 += 32){
    short8 av  = *(const short8*)(A + (size_t)(m0 + sr)*128 + k0 + sc);
    short8 wvv = *(const short8*)(W + (size_t)(n0 + sr)*128 + k0 + sc);
    __syncthreads();
    *(short8*)(Asm + sr*40 + sc) = av;
    *(short8*)(Bsm + sr*40 + sc) = wvv;
    __syncthreads();
    short8 af0 = *(const short8*)(Asm + (wm*32      + l15)*40 + quad*8);
    short8 af1 = *(const short8*)(Asm + (wm*32 + 16 + l15)*40 + quad*8);
    short8 bf0 = *(const short8*)(Bsm + (wn*32      + l15)*40 + quad*8);
    short8 bf1 = *(const short8*)(Bsm + (wn*32 + 16 + l15)*40 + quad*8);
    acc[0][0] = __builtin_amdgcn_mfma_f32_16x16x32_bf16(af0, bf0, acc[0][0], 0,0,0);
    acc[0][1] = __builtin_amdgcn_mfma_f32_16x16x32_bf16(af0, bf1, acc[0][1], 0,0,0);
    acc[1][0] = __builtin_amdgcn_mfma_f32_16x16x32_bf16(af1, bf0, acc[1][0], 0,0,0);
    acc[1][1] = __builtin_amdgcn_mfma_f32_16x16x32_bf16(af1, bf1, acc[1][1], 0,0,0);
  }
  #pragma unroll
  for (int ms = 0; ms < 2; ++ms)
    #pragma unroll
    for (int ns = 0; ns < 2; ++ns){
      int mb = m0 + wm*32 + ms*16 + quad*4;
      int nn = n0 + wn*32 + ns*16 + l15;
      int which = nn >> 7, col = nn & 127, h = col >> 5, hd = col & 31;
      f32x4 c = acc[ms][ns];
      #pragma unroll
      for (int r = 0; r < 4; ++r){
        int m = mb + r, b = m >> 11, s = m & 2047;
        if (which == 0)      qh[((size_t)(b*H_+h)*S_ + s)*32 + hd] = f2bf(c[r]);
        else if (which == 1) kh[((size_t)(b*H_+h)*S_ + s)*32 + hd] = f2bf(c[r]);
        else                 vt[((size_t)(b*H_+h)*32 + hd)*S_ + s] = f2bf(c[r]);
      }
    }
}

// ---------------------------------------------------------------- fused attention
template<bool WRITE_AW>
__global__ __launch_bounds__(256) void attn_k(const u16* __restrict__ qh, const u16* __restrict__ kh,
    const u16* __restrict__ vT, u16* __restrict__ ao_bf, float* __restrict__ aw){
  __shared__ u16 Ks[64*40];
  __shared__ u16 Vs[32*72];
  __shared__ u16 Ps[4*16*72];
  int bh = blockIdx.y; int b = bh >> 2, h = bh & 3;
  int q0 = blockIdx.x*64;
  int tid = threadIdx.x, wv = tid >> 6, lane = tid & 63, quad = lane >> 4, l15 = lane & 15;
  int qrow = q0 + wv*16 + l15;
  const size_t bhS = (size_t)bh * S_;
  short8 qf = *(const short8*)(qh + (bhS + qrow)*32 + quad*8);
  int kr = tid >> 2, kc = (tid & 3)*8;    // K tile [64][32]
  int vr = tid >> 3, vc = (tid & 7)*8;    // V^T tile [32][64]
  f32x4 zero = {0.f,0.f,0.f,0.f};
  f32x4 ao0 = zero, ao1 = zero;
  float lsum = 0.f, rinv = 1.0f;

  if constexpr (WRITE_AW){
    for (int k0 = 0; k0 < S_; k0 += 64){
      __syncthreads();
      *(short8*)(Ks + kr*40 + kc) = *(const short8*)(kh + (bhS + k0 + kr)*32 + kc);
      __syncthreads();
      #pragma unroll
      for (int jt = 0; jt < 4; ++jt){
        short8 kf = *(const short8*)(Ks + (jt*16 + l15)*40 + quad*8);
        f32x4 s = __builtin_amdgcn_mfma_f32_16x16x32_bf16(kf, qf, zero, 0,0,0);
        #pragma unroll
        for (int r = 0; r < 4; ++r) lsum += fexp2(s[r]*SCALE2_);
      }
    }
    lsum += __shfl_xor(lsum, 16, 64);
    lsum += __shfl_xor(lsum, 32, 64);
    rinv = 1.0f / lsum;
  }

  for (int k0 = 0; k0 < S_; k0 += 64){
    __syncthreads();
    *(short8*)(Ks + kr*40 + kc) = *(const short8*)(kh + (bhS + k0 + kr)*32 + kc);
    *(short8*)(Vs + vr*72 + vc) = *(const short8*)(vT + ((size_t)bh*32 + vr)*S_ + k0 + vc);
    __syncthreads();
    #pragma unroll
    for (int jt = 0; jt < 4; ++jt){
      short8 kf = *(const short8*)(Ks + (jt*16 + l15)*40 + quad*8);
      f32x4 s = __builtin_amdgcn_mfma_f32_16x16x32_bf16(kf, qf, zero, 0,0,0);
      float pv[4];
      #pragma unroll
      for (int r = 0; r < 4; ++r){
        float e = fexp2(s[r]*SCALE2_);
        if constexpr (WRITE_AW) e *= rinv; else lsum += e;
        pv[r] = e;
      }
      if constexpr (WRITE_AW){
        f32x4 st = {pv[0], pv[1], pv[2], pv[3]};
        *(f32x4*)(aw + (bhS + qrow)*S_ + k0 + jt*16 + quad*4) = st;
      }
      short4v pk;
      pk[0] = (short)f2bf(pv[0]); pk[1] = (short)f2bf(pv[1]);
      pk[2] = (short)f2bf(pv[2]); pk[3] = (short)f2bf(pv[3]);
      *(short4v*)(Ps + (wv*16 + l15)*72 + jt*16 + quad*4) = pk;
    }
    __asm__ volatile("s_waitcnt lgkmcnt(0)" ::: "memory");
    #pragma unroll
    for (int jg = 0; jg < 2; ++jg){
      short8 pf  = *(const short8*)(Ps + (wv*16 + l15)*72 + jg*32 + quad*8);
      short8 vf0 = *(const short8*)(Vs + (l15     )*72 + jg*32 + quad*8);
      short8 vf1 = *(const short8*)(Vs + (16 + l15)*72 + jg*32 + quad*8);
      ao0 = __builtin_amdgcn_mfma_f32_16x16x32_bf16(vf0, pf, ao0, 0,0,0);
      ao1 = __builtin_amdgcn_mfma_f32_16x16x32_bf16(vf1, pf, ao1, 0,0,0);
    }
  }

  if constexpr (!WRITE_AW){
    lsum += __shfl_xor(lsum, 16, 64);
    lsum += __shfl_xor(lsum, 32, 64);
    rinv = 1.0f / lsum;
  } else rinv = 1.0f;

  size_t rowbase = ((size_t)(b*S_ + qrow))*D_ + h*32;
  #pragma unroll
  for (int dt = 0; dt < 2; ++dt){
    f32x4 a = dt ? ao1 : ao0;
    short4v pk;
    #pragma unroll
    for (int r = 0; r < 4; ++r) pk[r] = (short)f2bf(a[r]*rinv);
    *(short4v*)(ao_bf + rowbase + dt*16 + quad*4) = pk;
  }
}

// ---------------------------------------------------------------- fused WO + gate
__global__ __launch_bounds__(256) void wowg_k(const u16* __restrict__ cin,
    const u16* __restrict__ ao_bf, const u16* __restrict__ wo, const u16* __restrict__ wg,
    const float* __restrict__ bo, const float* __restrict__ bg, u16* __restrict__ cout){
  __shared__ u16 aoS[16*136];
  __shared__ u16 cuS[16*136];
  __shared__ u16 outS[16*136];
  const int m0 = blockIdx.x*16;
  int tid = threadIdx.x, wv = tid >> 6, lane = tid & 63, quad = lane >> 4, l15 = lane & 15;
  {
    int row = tid >> 4, seg = (tid & 15)*8;
    *(short8*)(aoS + row*136 + seg) = *(const short8*)(ao_bf + (size_t)(m0+row)*128 + seg);
    *(short8*)(cuS + row*136 + seg) = *(const short8*)(cin   + (size_t)(m0+row)*128 + seg);
  }
  __syncthreads();
  f32x4 oacc[2] = {(f32x4){0,0,0,0},(f32x4){0,0,0,0}};
  #pragma unroll
  for (int kc = 0; kc < 4; ++kc){
    short8 af = *(const short8*)(aoS + l15*136 + kc*32 + quad*8);
    #pragma unroll
    for (int nt = 0; nt < 2; ++nt){
      int n = wv*32 + nt*16 + l15;
      short8 bfv = *(const short8*)(wo + (size_t)n*128 + kc*32 + quad*8);
      oacc[nt] = __builtin_amdgcn_mfma_f32_16x16x32_bf16(af, bfv, oacc[nt], 0,0,0);
    }
  }
  #pragma unroll
  for (int nt = 0; nt < 2; ++nt){
    int n = wv*32 + nt*16 + l15;
    float bias = bo[n];
    #pragma unroll
    for (int r = 0; r < 4; ++r){
      int m = quad*4 + r;
      outS[m*136 + n] = f2bf(oacc[nt][r] + bias);
    }
  }
  __syncthreads();
  f32x4 gacc[2] = {(f32x4){0,0,0,0},(f32x4){0,0,0,0}};
  #pragma unroll
  for (int kc = 0; kc < 8; ++kc){
    short8 af = (kc < 4) ? *(const short8*)(cuS  + l15*136 + kc*32 + quad*8)
                         : *(const short8*)(outS + l15*136 + (kc-4)*32 + quad*8);
    #pragma unroll
    for (int nt = 0; nt < 2; ++nt){
      int n = wv*32 + nt*16 + l15;
      short8 bfv = *(const short8*)(wg + (size_t)n*256 + kc*32 + quad*8);
      gacc[nt] = __builtin_amdgcn_mfma_f32_16x16x32_bf16(af, bfv, gacc[nt], 0,0,0);
    }
  }
  #pragma unroll
  for (int nt = 0; nt < 2; ++nt){
    int n = wv*32 + nt*16 + l15;
    float biasg = bg[n], biaso = bo[n];
    #pragma unroll
    for (int r = 0; r < 4; ++r){
      int m = quad*4 + r;
      float g = sigm(gacc[nt][r] + biasg);
      float c = bf2f(cuS[m*136 + n]);
      float o = oacc[nt][r] + biaso;
      cout[(size_t)(m0+m)*128 + n] = f2bf(c + g*(o - c));
    }
  }
}

// ---------------------------------------------------------------- uber: TRP+FFN+Apophasis
__global__ __launch_bounds__(256) void uber_k(const u16* __restrict__ lnb,
    const float* __restrict__ space, const float* __restrict__ xbuf,
    const float* __restrict__ cv, const float* __restrict__ cn,
    const u16* __restrict__ wt, const float* __restrict__ bt,
    const u16* __restrict__ wsx, const float* __restrict__ bs,
    const u16* __restrict__ wr, const float* __restrict__ br, const float* __restrict__ fv,
    const u16* __restrict__ wop, const float* __restrict__ bop,
    const float* __restrict__ g_ffn, const float* __restrict__ b_ffn,
    const u16* __restrict__ w1, const float* __restrict__ b1,
    const u16* __restrict__ w2, const float* __restrict__ b2,
    const u16* __restrict__ wsg, const float* __restrict__ bsg,
    const float* __restrict__ g_apo, const float* __restrict__ b_apo,
    const u16* __restrict__ wn, const float* __restrict__ bn,
    float* __restrict__ out_x){
  __shared__ u16 xnS[16*136];     // lnb stage, later xn3, later xn4
  __shared__ u16 spS[16*136];     // space bf16
  __shared__ u16 CcS[16*200];     // [tv | cv | sv] bf16
  __shared__ float svF[16*64];
  __shared__ u16 RsS[16*72];
  __shared__ float xrF[16*128];   // xbuf rows f32, updated in place
  __shared__ u16 midS[16*536];
  __shared__ float alignS[16];
  const int m0 = blockIdx.x*16;
  const int bidx = m0 >> 11;
  int tid = threadIdx.x, wv = tid >> 6, lane = tid & 63, quad = lane >> 4, l15 = lane & 15;

  // ---- stage
  {
    int row = tid >> 4, seg = (tid & 15)*8;
    *(short8*)(xnS + row*136 + seg) = *(const short8*)(lnb + (size_t)(m0+row)*128 + seg);
    const float* sp = space + (size_t)(m0+row)*128 + seg;
    short8 pk;
    #pragma unroll
    for (int i = 0; i < 8; ++i) pk[i] = (short)f2bf(sp[i]);
    *(short8*)(spS + row*136 + seg) = pk;
    f32x4 xa = *(const f32x4*)(xbuf + (size_t)(m0+row)*128 + seg);
    f32x4 xb = *(const f32x4*)(xbuf + (size_t)(m0+row)*128 + seg + 4);
    *(f32x4*)(xrF + row*128 + seg) = xa;
    *(f32x4*)(xrF + row*128 + seg + 4) = xb;
  }
  __syncthreads();

  // ---- S1: tv = xn2 @ Wt.T + bt
  f32x4 tvacc = {0,0,0,0};
  {
    int n = wv*16 + l15;
    #pragma unroll
    for (int kc = 0; kc < 4; ++kc){
      short8 af  = *(const short8*)(xnS + l15*136 + kc*32 + quad*8);
      short8 bfv = *(const short8*)(wt + (size_t)n*128 + kc*32 + quad*8);
      tvacc = __builtin_amdgcn_mfma_f32_16x16x32_bf16(af, bfv, tvacc, 0,0,0);
    }
    float bias = bt[n];
    #pragma unroll
    for (int r = 0; r < 4; ++r){
      tvacc[r] += bias;
      CcS[(quad*4 + r)*200 + n] = f2bf(tvacc[r]);
    }
  }
  // ---- S2: sv = space @ Ws.T + bs ; cv fill
  {
    int n = wv*16 + l15;
    f32x4 sva = {0,0,0,0};
    #pragma unroll
    for (int kc = 0; kc < 4; ++kc){
      short8 af  = *(const short8*)(spS + l15*136 + kc*32 + quad*8);
      short8 bfv = *(const short8*)(wsx + (size_t)n*128 + kc*32 + quad*8);
      sva = __builtin_amdgcn_mfma_f32_16x16x32_bf16(af, bfv, sva, 0,0,0);
    }
    float bias = bs[n];
    #pragma unroll
    for (int r = 0; r < 4; ++r){
      float v = sva[r] + bias;
      int m = quad*4 + r;
      CcS[m*200 + 128 + n] = f2bf(v);
      svF[m*64 + n] = v;
    }
    int row = tid >> 4, c4 = (tid & 15)*4;
    #pragma unroll
    for (int i = 0; i < 4; ++i)
      CcS[row*200 + 64 + c4 + i] = f2bf(cv[bidx*64 + c4 + i]);
  }
  __syncthreads();

  // ---- S3: align per row
  {
    float cnb = cn[bidx];
    for (int rr = wv*4; rr < wv*4 + 4; ++rr){
      float s = svF[rr*64 + lane];
      float c = cv[bidx*64 + lane];
      float dot = c*s, ss = s*s;
      #pragma unroll
      for (int m = 1; m < 64; m <<= 1){ dot += __shfl_xor(dot, m, 64); ss += __shfl_xor(ss, m, 64); }
      if (lane == 0){
        float sn = fmaxf(sqrtf(ss), 1e-8f);
        alignS[rr] = dot / (cnb * sn);
      }
    }
  }
  __syncthreads();

  // ---- S4: rgate (K=192) -> resolved -> RsS
  {
    int n = wv*16 + l15;
    f32x4 ra = {0,0,0,0};
    #pragma unroll
    for (int kc = 0; kc < 6; ++kc){
      short8 af  = *(const short8*)(CcS + l15*200 + kc*32 + quad*8);
      short8 bfv = *(const short8*)(wr + (size_t)n*192 + kc*32 + quad*8);
      ra = __builtin_amdgcn_mfma_f32_16x16x32_bf16(af, bfv, ra, 0,0,0);
    }
    float bias = br[n], fvn = fv[n];
    #pragma unroll
    for (int r = 0; r < 4; ++r){
      int m = quad*4 + r;
      float rg = sigm(ra[r] + bias);
      float t = tvacc[r];
      float res = t + TRP_*(-alignS[m]*(fvn - t)*rg);
      RsS[m*72 + n] = f2bf(res);
    }
  }
  __syncthreads();

  // ---- S5: x += resolved @ Wop.T + bop
  {
    f32x4 wa[2] = {(f32x4){0,0,0,0},(f32x4){0,0,0,0}};
    #pragma unroll
    for (int kc = 0; kc < 2; ++kc){
      short8 af = *(const short8*)(RsS + l15*72 + kc*32 + quad*8);
      #pragma unroll
      for (int nt = 0; nt < 2; ++nt){
        int n = wv*32 + nt*16 + l15;
        short8 bfv = *(const short8*)(wop + (size_t)n*64 + kc*32 + quad*8);
        wa[nt] = __builtin_amdgcn_mfma_f32_16x16x32_bf16(af, bfv, wa[nt], 0,0,0);
      }
    }
    #pragma unroll
    for (int nt = 0; nt < 2; ++nt){
      int n = wv*32 + nt*16 + l15;
      float bias = bop[n];
      #pragma unroll
      for (int r = 0; r < 4; ++r){
        int m = quad*4 + r;
        xrF[m*128 + n] += wa[nt][r] + bias;
      }
    }
  }
  __syncthreads();

  // ---- S6: xn3 = LN(x) with g_ffn -> xnS
  for (int rr = wv*4; rr < wv*4 + 4; ++rr){
    float v0 = xrF[rr*128 + lane], v1 = xrF[rr*128 + lane + 64];
    float s = v0 + v1;
    #pragma unroll
    for (int m = 1; m < 64; m <<= 1) s += __shfl_xor(s, m, 64);
    float mean = s * (1.0f/128.0f);
    float d0 = v0 - mean, d1 = v1 - mean;
    float vvv = d0*d0 + d1*d1;
    #pragma unroll
    for (int m = 1; m < 64; m <<= 1) vvv += __shfl_xor(vvv, m, 64);
    float rstd = rsqrtf(vvv * (1.0f/128.0f) + EPS_);
    xnS[rr*136 + lane]      = f2bf(d0*rstd*g_ffn[lane]    + b_ffn[lane]);
    xnS[rr*136 + lane + 64] = f2bf(d1*rstd*g_ffn[lane+64] + b_ffn[lane+64]);
  }
  __syncthreads();

  // ---- S7: mid = gelu(xn3 @ W1.T + b1)
  {
    f32x4 acc[8];
    #pragma unroll
    for (int i = 0; i < 8; ++i) acc[i] = (f32x4){0,0,0,0};
    #pragma unroll
    for (int kc = 0; kc < 4; ++kc){
      short8 af = *(const short8*)(xnS + l15*136 + kc*32 + quad*8);
      #pragma unroll
      for (int nt = 0; nt < 8; ++nt){
        int n = wv*128 + nt*16 + l15;
        short8 bfv = *(const short8*)(w1 + (size_t)n*128 + kc*32 + quad*8);
        acc[nt] = __builtin_amdgcn_mfma_f32_16x16x32_bf16(af, bfv, acc[nt], 0,0,0);
      }
    }
    #pragma unroll
    for (int nt = 0; nt < 8; ++nt){
      int n = wv*128 + nt*16 + l15;
      float bias = b1[n];
      #pragma unroll
      for (int r = 0; r < 4; ++r){
        int m = quad*4 + r;
        float lin = acc[nt][r] + bias;
        float ge = 0.5f*lin*(1.0f + erff(lin*0.70710678118654752f));
        midS[m*536 + n] = f2bf(ge);
      }
    }
  }
  __syncthreads();

  // ---- S8+S9: ff = mid @ W2.T + b2 ; sg = sigm(xn3 @ Wsg.T + bsg); x += sg*ff
  {
    f32x4 ffa[2] = {(f32x4){0,0,0,0},(f32x4){0,0,0,0}};
    #pragma unroll
    for (int kc = 0; kc < 16; ++kc){
      short8 af = *(const short8*)(midS + l15*536 + kc*32 + quad*8);
      #pragma unroll
      for (int nt = 0; nt < 2; ++nt){
        int n = wv*32 + nt*16 + l15;
        short8 bfv = *(const short8*)(w2 + (size_t)n*512 + kc*32 + quad*8);
        ffa[nt] = __builtin_amdgcn_mfma_f32_16x16x32_bf16(af, bfv, ffa[nt], 0,0,0);
      }
    }
    f32x4 sga[2] = {(f32x4){0,0,0,0},(f32x4){0,0,0,0}};
    #pragma unroll
    for (int kc = 0; kc < 4; ++kc){
      short8 af = *(const short8*)(xnS + l15*136 + kc*32 + quad*8);
      #pragma unroll
      for (int nt = 0; nt < 2; ++nt){
        int n = wv*32 + nt*16 + l15;
        short8 bfv = *(const short8*)(wsg + (size_t)n*128 + kc*32 + quad*8);
        sga[nt] = __builtin_amdgcn_mfma_f32_16x16x32_bf16(af, bfv, sga[nt], 0,0,0);
      }
    }
    #pragma unroll
    for (int nt = 0; nt < 2; ++nt){
      int n = wv*32 + nt*16 + l15;
      float b2n = b2[n], bsgn = bsg[n];
      #pragma unroll
      for (int r = 0; r < 4; ++r){
        int m = quad*4 + r;
        float ff = ffa[nt][r] + b2n;
        float sg = sigm(sga[nt][r] + bsgn);
        xrF[m*128 + n] += sg*ff;
      }
    }
  }
  __syncthreads();

  // ---- S10: xn4 = LN(x) with g_apo -> xnS
  for (int rr = wv*4; rr < wv*4 + 4; ++rr){
    float v0 = xrF[rr*128 + lane], v1 = xrF[rr*128 + lane + 64];
    float s = v0 + v1;
    #pragma unroll
    for (int m = 1; m < 64; m <<= 1) s += __shfl_xor(s, m, 64);
    float mean = s * (1.0f/128.0f);
    float d0 = v0 - mean, d1 = v1 - mean;
    float vvv = d0*d0 + d1*d1;
    #pragma unroll
    for (int m = 1; m < 64; m <<= 1) vvv += __shfl_xor(vvv, m, 64);
    float rstd = rsqrtf(vvv * (1.0f/128.0f) + EPS_);
    xnS[rr*136 + lane]      = f2bf(d0*rstd*g_apo[lane]    + b_apo[lane]);
    xnS[rr*136 + lane + 64] = f2bf(d1*rstd*g_apo[lane+64] + b_apo[lane+64]);
  }
  __syncthreads();

  // ---- S11: out = x - APO*tanh(xn4 @ Wn.T + bn)
  {
    f32x4 na[2] = {(f32x4){0,0,0,0},(f32x4){0,0,0,0}};
    #pragma unroll
    for (int kc = 0; kc < 4; ++kc){
      short8 af = *(const short8*)(xnS + l15*136 + kc*32 + quad*8);
      #pragma unroll
      for (int nt = 0; nt < 2; ++nt){
        int n = wv*32 + nt*16 + l15;
        short8 bfv = *(const short8*)(wn + (size_t)n*128 + kc*32 + quad*8);
        na[nt] = __builtin_amdgcn_mfma_f32_16x16x32_bf16(af, bfv, na[nt], 0,0,0);
      }
    }
    #pragma unroll
    for (int nt = 0; nt < 2; ++nt){
      int n = wv*32 + nt*16 + l15;
      float bias = bn[n];
      #pragma unroll
      for (int r = 0; r < 4; ++r){
        int m = quad*4 + r;
        out_x[(size_t)(m0+m)*128 + n] = xrF[m*128 + n] - APO_*tanhf(na[nt][r] + bias);
      }
    }
  }
}

// ---------------------------------------------------------------- launch
extern "C" void kernel_launch(void* const* d_in, const int* in_sizes, int n_in,
                              void* d_out, int out_size, void* d_ws, size_t ws_size,
                              hipStream_t stream){
  (void)in_sizes; (void)n_in; (void)out_size; (void)ws_size;
  const float* x_in   = (const float*)d_in[0];
  const float* space  = (const float*)d_in[1];
  const float* g_attn = (const float*)d_in[2];
  const float* b_attn = (const float*)d_in[3];
  const float* Wq     = (const float*)d_in[4];
  const float* Wk     = (const float*)d_in[5];
  const float* Wv     = (const float*)d_in[6];
  const float* Wo     = (const float*)d_in[7];
  const float* bo     = (const float*)d_in[8];
  const float* Wg     = (const float*)d_in[9];
  const float* bg     = (const float*)d_in[10];
  const float* g_trp  = (const float*)d_in[13];
  const float* b_trp  = (const float*)d_in[14];
  const float* Wt     = (const float*)d_in[15];
  const float* bt     = (const float*)d_in[16];
  const float* Wc     = (const float*)d_in[17];
  const float* bc     = (const float*)d_in[18];
  const float* Ws_    = (const float*)d_in[19];
  const float* bs     = (const float*)d_in[20];
  const float* Wr     = (const float*)d_in[21];
  const float* br     = (const float*)d_in[22];
  const float* fv     = (const float*)d_in[23];
  const float* Wop    = (const float*)d_in[24];
  const float* bop    = (const float*)d_in[25];
  const float* g_ffn  = (const float*)d_in[26];
  const float* b_ffn  = (const float*)d_in[27];
  const float* W1_    = (const float*)d_in[28];
  const float* b1     = (const float*)d_in[29];
  const float* W2_    = (const float*)d_in[30];
  const float* b2     = (const float*)d_in[31];
  const float* Wsg_   = (const float*)d_in[32];
  const float* bsg    = (const float*)d_in[33];
  const float* g_apo  = (const float*)d_in[34];
  const float* b_apo  = (const float*)d_in[35];
  const float* Wn_    = (const float*)d_in[36];
  const float* bn     = (const float*)d_in[37];

  char* base = (char*)d_ws;
  size_t off = 0;
  auto alloc = [&](size_t bytes)->char* {
    char* r = base + off; off += (bytes + 255) & ~(size_t)255; return r; };
  u16*  wbf   = (u16*) alloc((size_t)299008*2);
  u16*  cg0   = (u16*) alloc((size_t)M_*D_*2);
  u16*  cg1   = (u16*) alloc((size_t)M_*D_*2);
  u16*  qh    = (u16*) alloc((size_t)16*S_*32*2);
  u16*  kh    = (u16*) alloc((size_t)16*S_*32*2);
  u16*  vt    = (u16*) alloc((size_t)16*32*S_*2);
  u16*  ao_bf = (u16*) alloc((size_t)M_*D_*2);
  u16*  lnb   = (u16*) alloc((size_t)M_*D_*2);
  float* xbuf = (float*)alloc((size_t)M_*D_*4);
  float* colmean = (float*)alloc(4*128*4);
  float* cvb  = (float*)alloc(4*64*4);
  float* cnb  = (float*)alloc(4*4);

  u16* wqkv = wbf;           // [384,128]
  u16* wo   = wbf + 49152;   // [128,128]
  u16* wg   = wbf + 65536;   // [128,256]
  u16* wt   = wbf + 98304;   // [64,128]
  u16* wsx  = wbf + 106496;  // [64,128]
  u16* wr   = wbf + 114688;  // [64,192]
  u16* wop  = wbf + 126976;  // [128,64]
  u16* w1   = wbf + 135168;  // [512,128]
  u16* w2   = wbf + 200704;  // [128,512]
  u16* wsgp = wbf + 266240;  // [128,128]
  u16* wn   = wbf + 282624;  // [128,128]

  float* out_x = (float*)d_out;
  float* aw    = out_x + (size_t)M_*D_;

  WSrc wsrc;
  wsrc.s[0]=Wq; wsrc.s[1]=Wk; wsrc.s[2]=Wv; wsrc.s[3]=Wo; wsrc.s[4]=Wg;
  wsrc.s[5]=Wt; wsrc.s[6]=Ws_; wsrc.s[7]=Wr; wsrc.s[8]=Wop; wsrc.s[9]=W1_;
  wsrc.s[10]=W2_; wsrc.s[11]=Wsg_; wsrc.s[12]=Wn_;

  cvt_weights<<<1168, 256, 0, stream>>>(wsrc, wbf);
  ln_kernel<<<M_/4, 256, 0, stream>>>(x_in, nullptr, g_attn, b_attn, nullptr, cg0);

  u16* cgs[2] = {cg0, cg1};
  for (int it = 0; it < 3; ++it){
    u16* cin  = cgs[it & 1];
    u16* cout = cgs[(it + 1) & 1];
    gemm_qkv<<<dim3(M_/64, 6), 256, 0, stream>>>(cin, wqkv, qh, kh, vt);
    if (it == 2) attn_k<true ><<<dim3(S_/64, 16), 256, 0, stream>>>(qh, kh, vt, ao_bf, aw);
    else         attn_k<false><<<dim3(S_/64, 16), 256, 0, stream>>>(qh, kh, vt, ao_bf, nullptr);
    wowg_k<<<M_/16, 256, 0, stream>>>(cin, ao_bf, wo, wg, bo, bg, cout);
  }

  ln_kernel<<<M_/4, 256, 0, stream>>>(x_in, cg1, g_trp, b_trp, xbuf, lnb);
  colmean_k<<<4, 256, 0, stream>>>(lnb, colmean);
  cv_k<<<1, 256, 0, stream>>>(colmean, Wc, bc, cvb, cnb);

  uber_k<<<M_/16, 256, 0, stream>>>(lnb, space, xbuf, cvb, cnb,
      wt, bt, wsx, bs, wr, br, fv, wop, bop,
      g_ffn, b_ffn, w1, b1, w2, b2, wsgp, bsg,
      g_apo, b_apo, wn, bn, out_x);
}